// Round 18
// baseline (1009.009 us; speedup 1.0000x reference)
//
#include <hip/hip_runtime.h>
#include <math.h>

#define N_ROWS 65536
#define DIM    256
#define NCODE  4096
#define MARGIN 2e-4f
#define TILE_C 32
#define NTILE  (NCODE / TILE_C)   // 128
#define FB     8                  // fixup rows per batch
#define KCH    1024               // fixup codes per chunk
#define NCH    (NCODE / KCH)      // 4
#define FIXG   512

typedef __attribute__((ext_vector_type(8)))  short short8v;
typedef __attribute__((ext_vector_type(4)))  float float4v;
typedef __attribute__((ext_vector_type(16))) float f32x16;

__device__ inline unsigned short f2bf(float f) {
    unsigned u = __float_as_uint(f);
    unsigned r = (u + 0x7fffu + ((u >> 16) & 1u)) >> 16;
    return (unsigned short)r;
}
__device__ inline float bf2f(unsigned short h) {
    return __uint_as_float(((unsigned)h) << 16);
}
__device__ inline void gll16(const void* g, void* l) {
    __builtin_amdgcn_global_load_lds(
        (const __attribute__((address_space(1))) unsigned int*)g,
        (__attribute__((address_space(3))) unsigned int*)l, 16, 0, 0);
}

// ---------------- codebook normalize: PACKED bf16 split chunks (pk), c2 (fp32), c2d/ndi (f64)
// pk chunk = (cb32*16 + ks)*2 + hl (1KB each); slot = lane*8 + j, lane = hi*32+klo (A-frag order)
__global__ void cb_norm_kernel(const float* __restrict__ cb,
                               unsigned short* __restrict__ pk,
                               float* __restrict__ c2,
                               double* __restrict__ c2d,
                               double* __restrict__ ndi) {
    int k = blockIdx.x;
    int t = threadIdx.x;
    float v = cb[k * DIM + t];
    double dv = (double)v;
    double ss = dv * dv;
    __shared__ double red2[4], red3[4], redn[4];
    #pragma unroll
    for (int off = 32; off > 0; off >>= 1) ss += __shfl_down(ss, off);
    if ((t & 63) == 0) redn[t >> 6] = ss;
    __syncthreads();
    double S = redn[0] + redn[1] + redn[2] + redn[3];
    double nrm = fmax(sqrt(S), 1e-12);
    double cq = dv / nrm;
    float cf = (float)cq;
    unsigned short hb = f2bf(cf);
    unsigned short lb = f2bf(cf - bf2f(hb));
    {
        int cb32 = k >> 5, klo = k & 31, ks = t >> 4, hi = (t >> 3) & 1, j = t & 7;
        size_t ch = ((size_t)cb32 * 16 + ks) * 2;
        size_t slot = (size_t)(hi * 32 + klo) * 8 + j;
        pk[(ch + 0) * 512 + slot] = hb;
        pk[(ch + 1) * 512 + slot] = lb;
    }
    double s2 = (double)cf * (double)cf;
    double s3 = cq * cq;
    #pragma unroll
    for (int off = 32; off > 0; off >>= 1) {
        s2 += __shfl_down(s2, off);
        s3 += __shfl_down(s3, off);
    }
    if ((t & 63) == 0) { red2[t >> 6] = s2; red3[t >> 6] = s3; }
    __syncthreads();
    if (t == 0) {
        c2[k]  = (float)(red2[0] + red2[1] + red2[2] + red2[3]);
        c2d[k] = red3[0] + red3[1] + red3[2] + red3[3];
        ndi[k] = 1.0 / nrm;
    }
}

// ---------------- per-row x norms in f64; zero the fixup counter
__global__ void x_norm_kernel(const float* __restrict__ x,
                              float* __restrict__ nx,
                              float* __restrict__ scx,
                              int* __restrict__ counter) {
    if (blockIdx.x == 0 && threadIdx.x == 0) counter[0] = 0;
    int w = threadIdx.x >> 6;
    int lane = threadIdx.x & 63;
    int row = blockIdx.x * 4 + w;
    float4 v = ((const float4*)(x + (size_t)row * DIM))[lane];
    double ss = (double)v.x * v.x + (double)v.y * v.y
              + (double)v.z * v.z + (double)v.w * v.w;
    #pragma unroll
    for (int off = 32; off > 0; off >>= 1) ss += __shfl_down(ss, off);
    if (lane == 0) {
        double n = fmax(sqrt(ss), 1e-12);
        nx[row]  = (float)n;
        scx[row] = (float)(2.0 / n);
    }
}

// ---------------- main: 3-pass split-bf16 32x32x16 MFMA + EXACT top-2 + gap flag.
// 64 x-rows per wave (2 row-groups): each A-fragment LDS read feeds 6 MFMAs,
// halving LDS-read traffic per row. Block = 4 waves = 256 rows; grid = 256.
__attribute__((amdgpu_waves_per_eu(2, 2)))
__global__ void __launch_bounds__(256)
argmin_mfma_kernel(const float* __restrict__ x,
                   const unsigned short* __restrict__ pk,
                   const float* __restrict__ c2,
                   const float* __restrict__ scx,
                   int* __restrict__ idx_out,
                   int* __restrict__ counter,
                   int* __restrict__ rowlist) {
    __shared__ unsigned short buf[2][16384];   // 2 x 32KB
    __shared__ float c2s[NCODE];               // 16KB

    int tid  = threadIdx.x;
    int lane = tid & 63;
    int wave = tid >> 6;
    int cl31 = lane & 31;
    int hi   = lane >> 5;
    int xbase = blockIdx.x * 256 + wave * 64;  // 64 rows per wave

    // ---- stage c2 into LDS (once)
    #pragma unroll
    for (int i = 0; i < NCODE / 256; i++) c2s[i * 256 + tid] = c2[i * 256 + tid];

    // ---- load + split X fragments for both row-groups (rg0: +cl31, rg1: +32+cl31)
    short8v bh0[16], bl0[16], bh1[16], bl1[16];
    {
        const float* xr0 = x + (size_t)(xbase + cl31) * DIM + hi * 8;
        const float* xr1 = x + (size_t)(xbase + 32 + cl31) * DIM + hi * 8;
        #pragma unroll
        for (int ks = 0; ks < 16; ks++) {
            float4 f0 = *(const float4*)(xr0 + ks * 16);
            float4 f1 = *(const float4*)(xr0 + ks * 16 + 4);
            float e[8] = {f0.x, f0.y, f0.z, f0.w, f1.x, f1.y, f1.z, f1.w};
            short8v h, l;
            #pragma unroll
            for (int j = 0; j < 8; j++) {
                unsigned short hb = f2bf(e[j]);
                h[j] = (short)hb;
                l[j] = (short)f2bf(e[j] - bf2f(hb));
            }
            bh0[ks] = h;
            bl0[ks] = l;
        }
        #pragma unroll
        for (int ks = 0; ks < 16; ks++) {
            float4 f0 = *(const float4*)(xr1 + ks * 16);
            float4 f1 = *(const float4*)(xr1 + ks * 16 + 4);
            float e[8] = {f0.x, f0.y, f0.z, f0.w, f1.x, f1.y, f1.z, f1.w};
            short8v h, l;
            #pragma unroll
            for (int j = 0; j < 8; j++) {
                unsigned short hb = f2bf(e[j]);
                h[j] = (short)hb;
                l[j] = (short)f2bf(e[j] - bf2f(hb));
            }
            bh1[ks] = h;
            bl1[ks] = l;
        }
    }
    float scr0 = scx[xbase + cl31];
    float scr1 = scx[xbase + 32 + cl31];

    float s1a = 3.4e38f, s2a = 3.4e38f, s1b = 3.4e38f, s2b = 3.4e38f;
    int   i1a = 0x7fffffff, i1b = 0x7fffffff;

    // ---- stage tile 0 (each wave: 8 chunks, linear 1KB each)
    {
        const unsigned short* src = pk + ((size_t)wave * 8) * 512 + lane * 8;
        unsigned short* dst = &buf[0][(wave * 8) * 512];
        #pragma unroll
        for (int i = 0; i < 8; i++) gll16(src + i * 512, dst + i * 512);
    }
    __syncthreads();

    int cur = 0;
    for (int t = 0; t < NTILE; t++) {
        int cbb = t * TILE_C;

        if (t + 1 < NTILE) {
            const unsigned short* src =
                pk + ((size_t)(t + 1) * 32 + wave * 8) * 512 + lane * 8;
            unsigned short* dst = &buf[cur ^ 1][(wave * 8) * 512];
            #pragma unroll
            for (int i = 0; i < 8; i++) gll16(src + i * 512, dst + i * 512);
        }

        // ---- 96 MFMA from LDS: each (ah, al) read feeds both row-groups
        const unsigned short* cbuf = &buf[cur][0];
        f32x16 a0 = {0.f,0.f,0.f,0.f,0.f,0.f,0.f,0.f,0.f,0.f,0.f,0.f,0.f,0.f,0.f,0.f};
        f32x16 a1 = a0;
        #pragma unroll
        for (int ks = 0; ks < 16; ks++) {
            short8v ah = *(const short8v*)(cbuf + (size_t)(ks * 2 + 0) * 512 + lane * 8);
            short8v al = *(const short8v*)(cbuf + (size_t)(ks * 2 + 1) * 512 + lane * 8);
            a0 = __builtin_amdgcn_mfma_f32_32x32x16_bf16(ah, bh0[ks], a0, 0, 0, 0);
            a1 = __builtin_amdgcn_mfma_f32_32x32x16_bf16(ah, bh1[ks], a1, 0, 0, 0);
            a0 = __builtin_amdgcn_mfma_f32_32x32x16_bf16(ah, bl0[ks], a0, 0, 0, 0);
            a1 = __builtin_amdgcn_mfma_f32_32x32x16_bf16(ah, bl1[ks], a1, 0, 0, 0);
            a0 = __builtin_amdgcn_mfma_f32_32x32x16_bf16(al, bh0[ks], a0, 0, 0, 0);
            a1 = __builtin_amdgcn_mfma_f32_32x32x16_bf16(al, bh1[ks], a1, 0, 0, 0);
        }

        // ---- epilogue per row-group: exact best2 with wave-skip (R13 logic x2)
        float4v gq0 = *(const float4v*)&c2s[cbb + hi * 4];
        float4v gq1 = *(const float4v*)&c2s[cbb + hi * 4 + 8];
        float4v gq2 = *(const float4v*)&c2s[cbb + hi * 4 + 16];
        float4v gq3 = *(const float4v*)&c2s[cbb + hi * 4 + 24];
        float sva[16], svb[16];
        float mna = 3.4e38f, mnb = 3.4e38f;
        #pragma unroll
        for (int g = 0; g < 4; g++) {
            float4v gg = (g == 0) ? gq0 : (g == 1) ? gq1 : (g == 2) ? gq2 : gq3;
            #pragma unroll
            for (int q = 0; q < 4; q++) {
                int r = g * 4 + q;
                float sa = gg[q] - scr0 * a0[r];
                float sb = gg[q] - scr1 * a1[r];
                sva[r] = sa; svb[r] = sb;
                mna = fminf(mna, sa);
                mnb = fminf(mnb, sb);
            }
        }
        if (!__all(mna >= s2a)) {
            #pragma unroll
            for (int g = 0; g < 4; g++) {
                #pragma unroll
                for (int q = 0; q < 4; q++) {
                    float s = sva[g * 4 + q];
                    int ci = cbb + q + 8 * g + 4 * hi;   // ascending per thread
                    if (s < s1a) { s2a = s1a; s1a = s; i1a = ci; }
                    else if (s < s2a) s2a = s;
                }
            }
        }
        if (!__all(mnb >= s2b)) {
            #pragma unroll
            for (int g = 0; g < 4; g++) {
                #pragma unroll
                for (int q = 0; q < 4; q++) {
                    float s = svb[g * 4 + q];
                    int ci = cbb + q + 8 * g + 4 * hi;
                    if (s < s1b) { s2b = s1b; s1b = s; i1b = ci; }
                    else if (s < s2b) s2b = s;
                }
            }
        }

        __syncthreads();   // drains gll vmcnt; all waves done with cur
        cur ^= 1;
    }

    // ---- merge the two lane-halves (same row, disjoint codes): exact global top-2
    {
        float o1 = __shfl_xor(s1a, 32);
        int   oi = __shfl_xor(i1a, 32);
        float o2 = __shfl_xor(s2a, 32);
        if (o1 < s1a || (o1 == s1a && oi < i1a)) { s2a = fminf(s1a, o2); s1a = o1; i1a = oi; }
        else                                      { s2a = fminf(o1, s2a); }
        o1 = __shfl_xor(s1b, 32);
        oi = __shfl_xor(i1b, 32);
        o2 = __shfl_xor(s2b, 32);
        if (o1 < s1b || (o1 == s1b && oi < i1b)) { s2b = fminf(s1b, o2); s1b = o1; i1b = oi; }
        else                                      { s2b = fminf(o1, s2b); }
    }
    if (lane < 32) {
        int row = xbase + lane;
        idx_out[row] = i1a;
        if (s2a - s1a < MARGIN) { int slot = atomicAdd(counter, 1); rowlist[slot] = row; }
        row = xbase + 32 + lane;
        idx_out[row] = i1b;
        if (s2b - s1b < MARGIN) { int slot = atomicAdd(counter, 1); rowlist[slot] = row; }
    }
}

// ---------------- fixup 2D: (8-row batch) x (1024-code chunk) exact f64 partial argmin
__global__ void fixup2d_kernel(const float* __restrict__ x,
                               const float* __restrict__ cb,
                               const double* __restrict__ c2d,
                               const double* __restrict__ ndi,
                               const int* __restrict__ counter,
                               const int* __restrict__ rowlist,
                               double* __restrict__ pb_s,
                               int* __restrict__ pb_i) {
    __shared__ double xs[FB][DIM];        // 16KB
    __shared__ double isx_sh[FB];
    __shared__ double red_s[4][FB];
    __shared__ int    red_i[4][FB];
    int t = threadIdx.x, lane = t & 63, wave = t >> 6;
    int cnt = counter[0];
    int nbat = (cnt + FB - 1) / FB;
    int nwork = nbat * NCH;

    for (int w = blockIdx.x; w < nwork; w += FIXG) {
        int batch = w / NCH, chunk = w - batch * NCH;
        int base = batch * FB;
        int nb = cnt - base; if (nb > FB) nb = FB;

        #pragma unroll
        for (int r = 0; r < FB; r++)
            if (r < nb) xs[r][t] = (double)x[(size_t)rowlist[base + r] * DIM + t];
        __syncthreads();

        for (int rr = wave; rr < nb; rr += 4) {
            double a0 = xs[rr][lane],       a1 = xs[rr][lane + 64];
            double a2 = xs[rr][lane + 128], a3 = xs[rr][lane + 192];
            double ss = a0 * a0 + a1 * a1 + a2 * a2 + a3 * a3;
            #pragma unroll
            for (int m = 1; m < 64; m <<= 1) ss += __shfl_xor(ss, m);
            if (lane == 0) isx_sh[rr] = 2.0 / fmax(sqrt(ss), 1e-12);
        }
        __syncthreads();

        double bs[FB]; int bi[FB];
        #pragma unroll
        for (int r = 0; r < FB; r++) { bs[r] = 1e300; bi[r] = 0x7fffffff; }

        for (int k0 = 0; k0 < KCH / 256; k0++) {
            int k = chunk * KCH + k0 * 256 + t;
            const float4* cr = (const float4*)(cb + (size_t)k * DIM);
            double d[FB];
            #pragma unroll
            for (int r = 0; r < FB; r++) d[r] = 0.0;
            #pragma unroll 4
            for (int d4 = 0; d4 < DIM / 4; d4++) {
                float4 c = cr[d4];
                double cx = c.x, cy = c.y, cz = c.z, cw = c.w;
                int dd = d4 * 4;
                #pragma unroll
                for (int r = 0; r < FB; r++) {
                    d[r] = fma(cx, xs[r][dd],     d[r]);
                    d[r] = fma(cy, xs[r][dd + 1], d[r]);
                    d[r] = fma(cz, xs[r][dd + 2], d[r]);
                    d[r] = fma(cw, xs[r][dd + 3], d[r]);
                }
            }
            double ndik = ndi[k], c2k = c2d[k];
            #pragma unroll
            for (int r = 0; r < FB; r++) {
                double sc = c2k - isx_sh[r] * d[r] * ndik;
                if (sc < bs[r] || (sc == bs[r] && k < bi[r])) { bs[r] = sc; bi[r] = k; }
            }
        }

        #pragma unroll
        for (int r = 0; r < FB; r++) {
            double b = bs[r]; int idx = bi[r];
            #pragma unroll
            for (int m = 1; m < 64; m <<= 1) {
                double ob = __shfl_xor(b, m);
                int   oi = __shfl_xor(idx, m);
                if (ob < b || (ob == b && oi < idx)) { b = ob; idx = oi; }
            }
            if (lane == 0) { red_s[wave][r] = b; red_i[wave][r] = idx; }
        }
        __syncthreads();
        if (t < nb) {
            double b = red_s[0][t]; int idx = red_i[0][t];
            #pragma unroll
            for (int ww = 1; ww < 4; ww++) {
                double ob = red_s[ww][t]; int oi = red_i[ww][t];
                if (ob < b || (ob == b && oi < idx)) { b = ob; idx = oi; }
            }
            pb_s[(size_t)(base + t) * NCH + chunk] = b;
            pb_i[(size_t)(base + t) * NCH + chunk] = idx;
        }
        __syncthreads();
    }
}

// ---------------- merge chunk partials -> final exact idx for flagged rows
__global__ void fixmerge_kernel(const int* __restrict__ counter,
                                const int* __restrict__ rowlist,
                                const double* __restrict__ pb_s,
                                const int* __restrict__ pb_i,
                                int* __restrict__ idxv) {
    int cnt = counter[0];
    for (int s = blockIdx.x * 256 + threadIdx.x; s < cnt; s += gridDim.x * 256) {
        double b = pb_s[(size_t)s * NCH]; int idx = pb_i[(size_t)s * NCH];
        #pragma unroll
        for (int c = 1; c < NCH; c++) {
            double ob = pb_s[(size_t)s * NCH + c]; int oi = pb_i[(size_t)s * NCH + c];
            if (ob < b || (ob == b && oi < idx)) { b = ob; idx = oi; }
        }
        idxv[rowlist[s]] = idx;
    }
}

// ---------------- gather + per-row loss partial (4 rows/block, float4; cb * 1/||cb||)
__global__ void gather_loss_kernel(const float* __restrict__ x,
                                   const float* __restrict__ cb,
                                   const double* __restrict__ ndi,
                                   const float* __restrict__ nx,
                                   const int* __restrict__ idxv,
                                   float* __restrict__ out_q,
                                   float* __restrict__ out_idxf,
                                   float* __restrict__ partials) {
    int w = threadIdx.x >> 6, lane = threadIdx.x & 63;
    int row = blockIdx.x * 4 + w;
    int iv = idxv[row];
    float ndif = (float)ndi[iv];
    float inx = 1.0f / nx[row];
    float4 q4 = ((const float4*)(cb + (size_t)iv * DIM))[lane];
    float4 x4 = ((const float4*)(x + (size_t)row * DIM))[lane];
    float4 qq;
    qq.x = q4.x * ndif; qq.y = q4.y * ndif;
    qq.z = q4.z * ndif; qq.w = q4.w * ndif;
    ((float4*)(out_q + (size_t)row * DIM))[lane] = qq;
    float dx = qq.x - x4.x * inx;
    float dy = qq.y - x4.y * inx;
    float dz = qq.z - x4.z * inx;
    float dw = qq.w - x4.w * inx;
    float ss = dx * dx + dy * dy + dz * dz + dw * dw;
    #pragma unroll
    for (int off = 32; off > 0; off >>= 1) ss += __shfl_down(ss, off);
    if (lane == 0) {
        partials[row] = ss;
        out_idxf[row] = (float)iv;
    }
}

// ---------------- final deterministic loss reduction
__global__ void loss_reduce_kernel(const float* __restrict__ partials,
                                   float* __restrict__ out_loss) {
    int t = threadIdx.x;
    float s = 0.0f;
    for (int i = t; i < N_ROWS; i += 256) s += partials[i];
    __shared__ float red[4];
    #pragma unroll
    for (int off = 32; off > 0; off >>= 1) s += __shfl_down(s, off);
    if ((t & 63) == 0) red[t >> 6] = s;
    __syncthreads();
    if (t == 0) out_loss[0] = 1.25f * (red[0] + red[1] + red[2] + red[3]) / (float)(N_ROWS * DIM);
}

extern "C" void kernel_launch(void* const* d_in, const int* in_sizes, int n_in,
                              void* d_out, int out_size, void* d_ws, size_t ws_size,
                              hipStream_t stream) {
    const float* x  = (const float*)d_in[0];
    const float* cb = (const float*)d_in[1];
    float* out = (float*)d_out;

    // doubles first (alignment), then f32/i32, then pk.  Total ~= 8.5 MB.
    double* c2d  = (double*)d_ws;                       // 4096 dbl
    double* ndi  = c2d + NCODE;                         // 4096 dbl
    double* pb_s = ndi + NCODE;                         // 65536*4 dbl (2MB)
    float*  c2   = (float*)(pb_s + (size_t)N_ROWS * NCH);  // 4096
    float*  nx   = c2 + NCODE;                          // 65536
    float*  scx  = nx + N_ROWS;                         // 65536
    int*    idxv = (int*)(scx + N_ROWS);                // 65536
    float*  partials = (float*)(idxv + N_ROWS);         // 65536
    int*    counter  = (int*)(partials + N_ROWS);       // 8 ints
    int*    rowlist  = counter + 8;                     // 65536
    int*    pb_i     = rowlist + N_ROWS;                // 65536*4 (1MB)
    unsigned short* pk = (unsigned short*)(pb_i + (size_t)N_ROWS * NCH);  // 4MB

    float* out_q    = out;
    float* out_loss = out + (size_t)N_ROWS * DIM;
    float* out_idxf = out_loss + 1;

    hipLaunchKernelGGL(cb_norm_kernel, dim3(NCODE), dim3(256), 0, stream,
                       cb, pk, c2, c2d, ndi);
    hipLaunchKernelGGL(x_norm_kernel, dim3(N_ROWS / 4), dim3(256), 0, stream, x, nx, scx, counter);
    hipLaunchKernelGGL(argmin_mfma_kernel, dim3(N_ROWS / 256), dim3(256), 0, stream,
                       x, pk, c2, scx, idxv, counter, rowlist);
    hipLaunchKernelGGL(fixup2d_kernel, dim3(FIXG), dim3(256), 0, stream,
                       x, cb, c2d, ndi, counter, rowlist, pb_s, pb_i);
    hipLaunchKernelGGL(fixmerge_kernel, dim3(64), dim3(256), 0, stream,
                       counter, rowlist, pb_s, pb_i, idxv);
    hipLaunchKernelGGL(gather_loss_kernel, dim3(N_ROWS / 4), dim3(256), 0, stream,
                       x, cb, ndi, nx, idxv, out_q, out_idxf, partials);
    hipLaunchKernelGGL(loss_reduce_kernel, dim3(1), dim3(256), 0, stream,
                       partials, out_loss);
}

// Round 19
// 599.144 us; speedup vs baseline: 1.6841x; 1.6841x over previous
//
#include <hip/hip_runtime.h>
#include <math.h>

#define N_ROWS 65536
#define DIM    256
#define NCODE  4096
#define MARGIN 2e-4f
#define TILE_C 32
#define NTILE  (NCODE / TILE_C)   // 128
#define FB     8                  // fixup rows per batch
#define KCH    1024               // fixup codes per chunk
#define NCH    (NCODE / KCH)      // 4
#define FIXG   512

typedef __attribute__((ext_vector_type(8)))  short short8v;
typedef __attribute__((ext_vector_type(4)))  float float4v;
typedef __attribute__((ext_vector_type(16))) float f32x16;

__device__ inline unsigned short f2bf(float f) {
    unsigned u = __float_as_uint(f);
    unsigned r = (u + 0x7fffu + ((u >> 16) & 1u)) >> 16;
    return (unsigned short)r;
}
__device__ inline float bf2f(unsigned short h) {
    return __uint_as_float(((unsigned)h) << 16);
}
__device__ inline void gll16(const void* g, void* l) {
    __builtin_amdgcn_global_load_lds(
        (const __attribute__((address_space(1))) unsigned int*)g,
        (__attribute__((address_space(3))) unsigned int*)l, 16, 0, 0);
}

// ---------------- fused prep: blocks [0,NCODE) = codebook normalize+pack,
// blocks [NCODE, NCODE+N_ROWS/4) = x norms (4 rows each) + counter zero.
__global__ void prep_kernel(const float* __restrict__ cb,
                            const float* __restrict__ x,
                            unsigned short* __restrict__ pk,
                            float* __restrict__ c2,
                            double* __restrict__ c2d,
                            double* __restrict__ ndi,
                            float* __restrict__ nx,
                            float* __restrict__ scx,
                            int* __restrict__ counter) {
    int t = threadIdx.x;
    if (blockIdx.x < NCODE) {
        int k = blockIdx.x;
        float v = cb[k * DIM + t];
        double dv = (double)v;
        double ss = dv * dv;
        __shared__ double red2[4], red3[4], redn[4];
        #pragma unroll
        for (int off = 32; off > 0; off >>= 1) ss += __shfl_down(ss, off);
        if ((t & 63) == 0) redn[t >> 6] = ss;
        __syncthreads();
        double S = redn[0] + redn[1] + redn[2] + redn[3];
        double nrm = fmax(sqrt(S), 1e-12);
        double cq = dv / nrm;
        float cf = (float)cq;
        unsigned short hb = f2bf(cf);
        unsigned short lb = f2bf(cf - bf2f(hb));
        {
            int cb32 = k >> 5, klo = k & 31, ks = t >> 4, hi = (t >> 3) & 1, j = t & 7;
            size_t ch = ((size_t)cb32 * 16 + ks) * 2;
            size_t slot = (size_t)(hi * 32 + klo) * 8 + j;
            pk[(ch + 0) * 512 + slot] = hb;
            pk[(ch + 1) * 512 + slot] = lb;
        }
        double s2 = (double)cf * (double)cf;
        double s3 = cq * cq;
        #pragma unroll
        for (int off = 32; off > 0; off >>= 1) {
            s2 += __shfl_down(s2, off);
            s3 += __shfl_down(s3, off);
        }
        if ((t & 63) == 0) { red2[t >> 6] = s2; red3[t >> 6] = s3; }
        __syncthreads();
        if (t == 0) {
            c2[k]  = (float)(red2[0] + red2[1] + red2[2] + red2[3]);
            c2d[k] = red3[0] + red3[1] + red3[2] + red3[3];
            ndi[k] = 1.0 / nrm;
        }
    } else {
        int xb = blockIdx.x - NCODE;
        if (xb == 0 && t == 0) counter[0] = 0;
        int w = t >> 6;
        int lane = t & 63;
        int row = xb * 4 + w;
        float4 v = ((const float4*)(x + (size_t)row * DIM))[lane];
        double ss = (double)v.x * v.x + (double)v.y * v.y
                  + (double)v.z * v.z + (double)v.w * v.w;
        #pragma unroll
        for (int off = 32; off > 0; off >>= 1) ss += __shfl_down(ss, off);
        if (lane == 0) {
            double n = fmax(sqrt(ss), 1e-12);
            nx[row]  = (float)n;
            scx[row] = (float)(2.0 / n);
        }
    }
}

// ---------------- main: 3-pass split-bf16 32x32x16 MFMA + EXACT top-2 + gap flag.
// R13 dbuf structure + triple accumulators + c2 pre-staged in LDS. (R17, proven)
__attribute__((amdgpu_waves_per_eu(2, 2)))
__global__ void __launch_bounds__(256)
argmin_mfma_kernel(const float* __restrict__ x,
                   const unsigned short* __restrict__ pk,
                   const float* __restrict__ c2,
                   const float* __restrict__ scx,
                   int* __restrict__ idx_out,
                   int* __restrict__ counter,
                   int* __restrict__ rowlist) {
    __shared__ unsigned short buf[2][16384];   // 2 x 32KB
    __shared__ float c2s[NCODE];               // 16KB

    int tid  = threadIdx.x;
    int lane = tid & 63;
    int wave = tid >> 6;
    int cl31 = lane & 31;
    int hi   = lane >> 5;
    int xbase = blockIdx.x * 128 + wave * 32;

    // ---- stage c2 into LDS (once)
    #pragma unroll
    for (int i = 0; i < NCODE / 256; i++) c2s[i * 256 + tid] = c2[i * 256 + tid];

    // ---- load + split X fragments: B-frag row = lane&31, k = hi*8+j
    short8v bh[16], bl[16];
    const float* xr = x + (size_t)(xbase + cl31) * DIM + hi * 8;
    #pragma unroll
    for (int ks = 0; ks < 16; ks++) {
        float4 f0 = *(const float4*)(xr + ks * 16);
        float4 f1 = *(const float4*)(xr + ks * 16 + 4);
        float e[8] = {f0.x, f0.y, f0.z, f0.w, f1.x, f1.y, f1.z, f1.w};
        short8v h, l;
        #pragma unroll
        for (int j = 0; j < 8; j++) {
            unsigned short hb = f2bf(e[j]);
            h[j] = (short)hb;
            l[j] = (short)f2bf(e[j] - bf2f(hb));
        }
        bh[ks] = h;
        bl[ks] = l;
    }
    float scr = scx[xbase + cl31];

    float s1 = 3.4e38f, s2 = 3.4e38f;
    int   i1 = 0x7fffffff;

    // ---- stage tile 0 (each wave: 8 chunks, linear 1KB each)
    {
        const unsigned short* src = pk + ((size_t)wave * 8) * 512 + lane * 8;
        unsigned short* dst = &buf[0][(wave * 8) * 512];
        #pragma unroll
        for (int i = 0; i < 8; i++) gll16(src + i * 512, dst + i * 512);
    }
    __syncthreads();

    int cur = 0;
    for (int t = 0; t < NTILE; t++) {
        int cbb = t * TILE_C;

        if (t + 1 < NTILE) {
            const unsigned short* src =
                pk + ((size_t)(t + 1) * 32 + wave * 8) * 512 + lane * 8;
            unsigned short* dst = &buf[cur ^ 1][(wave * 8) * 512];
            #pragma unroll
            for (int i = 0; i < 8; i++) gll16(src + i * 512, dst + i * 512);
        }

        // ---- 48 MFMA from LDS, 3 independent accumulator chains (len 16 each)
        const unsigned short* cbuf = &buf[cur][0];
        f32x16 a1 = {0.f,0.f,0.f,0.f,0.f,0.f,0.f,0.f,0.f,0.f,0.f,0.f,0.f,0.f,0.f,0.f};
        f32x16 a2 = a1, a3 = a1;
        #pragma unroll
        for (int ks = 0; ks < 16; ks++) {
            short8v ah = *(const short8v*)(cbuf + (size_t)(ks * 2 + 0) * 512 + lane * 8);
            short8v al = *(const short8v*)(cbuf + (size_t)(ks * 2 + 1) * 512 + lane * 8);
            a1 = __builtin_amdgcn_mfma_f32_32x32x16_bf16(ah, bh[ks], a1, 0, 0, 0);
            a2 = __builtin_amdgcn_mfma_f32_32x32x16_bf16(ah, bl[ks], a2, 0, 0, 0);
            a3 = __builtin_amdgcn_mfma_f32_32x32x16_bf16(al, bh[ks], a3, 0, 0, 0);
        }

        // ---- epilogue: scores from LDS c2; exact best2 with wave-skip
        float4v gq0 = *(const float4v*)&c2s[cbb + hi * 4];
        float4v gq1 = *(const float4v*)&c2s[cbb + hi * 4 + 8];
        float4v gq2 = *(const float4v*)&c2s[cbb + hi * 4 + 16];
        float4v gq3 = *(const float4v*)&c2s[cbb + hi * 4 + 24];
        float sv[16];
        float mn = 3.4e38f;
        #pragma unroll
        for (int g = 0; g < 4; g++) {
            float4v gg = (g == 0) ? gq0 : (g == 1) ? gq1 : (g == 2) ? gq2 : gq3;
            #pragma unroll
            for (int q = 0; q < 4; q++) {
                int r = g * 4 + q;
                float s = gg[q] - scr * (a1[r] + a2[r] + a3[r]);
                sv[r] = s;
                mn = fminf(mn, s);
            }
        }
        if (!__all(mn >= s2)) {
            #pragma unroll
            for (int g = 0; g < 4; g++) {
                #pragma unroll
                for (int q = 0; q < 4; q++) {
                    float s = sv[g * 4 + q];
                    int ci = cbb + q + 8 * g + 4 * hi;   // ascending per thread
                    if (s < s1) { s2 = s1; s1 = s; i1 = ci; }
                    else if (s < s2) s2 = s;
                }
            }
        }

        __syncthreads();   // drains gll vmcnt; all waves done with cur
        cur ^= 1;
    }

    // ---- merge the two lane-halves (same row, disjoint codes): exact global top-2
    {
        float o1 = __shfl_xor(s1, 32);
        int   oi = __shfl_xor(i1, 32);
        float o2 = __shfl_xor(s2, 32);
        if (o1 < s1 || (o1 == s1 && oi < i1)) { s2 = fminf(s1, o2); s1 = o1; i1 = oi; }
        else                                   { s2 = fminf(o1, s2); }
    }
    if (lane < 32) {
        int row = xbase + lane;
        idx_out[row] = i1;
        if (s2 - s1 < MARGIN) { int slot = atomicAdd(counter, 1); rowlist[slot] = row; }
    }
}

// ---------------- fixup 2D: (8-row batch) x (1024-code chunk) exact f64 partial argmin
__global__ void fixup2d_kernel(const float* __restrict__ x,
                               const float* __restrict__ cb,
                               const double* __restrict__ c2d,
                               const double* __restrict__ ndi,
                               const int* __restrict__ counter,
                               const int* __restrict__ rowlist,
                               double* __restrict__ pb_s,
                               int* __restrict__ pb_i) {
    __shared__ double xs[FB][DIM];        // 16KB
    __shared__ double isx_sh[FB];
    __shared__ double red_s[4][FB];
    __shared__ int    red_i[4][FB];
    int t = threadIdx.x, lane = t & 63, wave = t >> 6;
    int cnt = counter[0];
    int nbat = (cnt + FB - 1) / FB;
    int nwork = nbat * NCH;

    for (int w = blockIdx.x; w < nwork; w += FIXG) {
        int batch = w / NCH, chunk = w - batch * NCH;
        int base = batch * FB;
        int nb = cnt - base; if (nb > FB) nb = FB;

        #pragma unroll
        for (int r = 0; r < FB; r++)
            if (r < nb) xs[r][t] = (double)x[(size_t)rowlist[base + r] * DIM + t];
        __syncthreads();

        for (int rr = wave; rr < nb; rr += 4) {
            double a0 = xs[rr][lane],       a1 = xs[rr][lane + 64];
            double a2 = xs[rr][lane + 128], a3 = xs[rr][lane + 192];
            double ss = a0 * a0 + a1 * a1 + a2 * a2 + a3 * a3;
            #pragma unroll
            for (int m = 1; m < 64; m <<= 1) ss += __shfl_xor(ss, m);
            if (lane == 0) isx_sh[rr] = 2.0 / fmax(sqrt(ss), 1e-12);
        }
        __syncthreads();

        double bs[FB]; int bi[FB];
        #pragma unroll
        for (int r = 0; r < FB; r++) { bs[r] = 1e300; bi[r] = 0x7fffffff; }

        for (int k0 = 0; k0 < KCH / 256; k0++) {
            int k = chunk * KCH + k0 * 256 + t;
            const float4* cr = (const float4*)(cb + (size_t)k * DIM);
            double d[FB];
            #pragma unroll
            for (int r = 0; r < FB; r++) d[r] = 0.0;
            #pragma unroll 4
            for (int d4 = 0; d4 < DIM / 4; d4++) {
                float4 c = cr[d4];
                double cx = c.x, cy = c.y, cz = c.z, cw = c.w;
                int dd = d4 * 4;
                #pragma unroll
                for (int r = 0; r < FB; r++) {
                    d[r] = fma(cx, xs[r][dd],     d[r]);
                    d[r] = fma(cy, xs[r][dd + 1], d[r]);
                    d[r] = fma(cz, xs[r][dd + 2], d[r]);
                    d[r] = fma(cw, xs[r][dd + 3], d[r]);
                }
            }
            double ndik = ndi[k], c2k = c2d[k];
            #pragma unroll
            for (int r = 0; r < FB; r++) {
                double sc = c2k - isx_sh[r] * d[r] * ndik;
                if (sc < bs[r] || (sc == bs[r] && k < bi[r])) { bs[r] = sc; bi[r] = k; }
            }
        }

        #pragma unroll
        for (int r = 0; r < FB; r++) {
            double b = bs[r]; int idx = bi[r];
            #pragma unroll
            for (int m = 1; m < 64; m <<= 1) {
                double ob = __shfl_xor(b, m);
                int   oi = __shfl_xor(idx, m);
                if (ob < b || (ob == b && oi < idx)) { b = ob; idx = oi; }
            }
            if (lane == 0) { red_s[wave][r] = b; red_i[wave][r] = idx; }
        }
        __syncthreads();
        if (t < nb) {
            double b = red_s[0][t]; int idx = red_i[0][t];
            #pragma unroll
            for (int ww = 1; ww < 4; ww++) {
                double ob = red_s[ww][t]; int oi = red_i[ww][t];
                if (ob < b || (ob == b && oi < idx)) { b = ob; idx = oi; }
            }
            pb_s[(size_t)(base + t) * NCH + chunk] = b;
            pb_i[(size_t)(base + t) * NCH + chunk] = idx;
        }
        __syncthreads();
    }
}

// ---------------- merge chunk partials -> final exact idx for flagged rows
__global__ void fixmerge_kernel(const int* __restrict__ counter,
                                const int* __restrict__ rowlist,
                                const double* __restrict__ pb_s,
                                const int* __restrict__ pb_i,
                                int* __restrict__ idxv) {
    int cnt = counter[0];
    for (int s = blockIdx.x * 256 + threadIdx.x; s < cnt; s += gridDim.x * 256) {
        double b = pb_s[(size_t)s * NCH]; int idx = pb_i[(size_t)s * NCH];
        #pragma unroll
        for (int c = 1; c < NCH; c++) {
            double ob = pb_s[(size_t)s * NCH + c]; int oi = pb_i[(size_t)s * NCH + c];
            if (ob < b || (ob == b && oi < idx)) { b = ob; idx = oi; }
        }
        idxv[rowlist[s]] = idx;
    }
}

// ---------------- gather + per-row loss partial (4 rows/block, float4; cb * 1/||cb||)
__global__ void gather_loss_kernel(const float* __restrict__ x,
                                   const float* __restrict__ cb,
                                   const double* __restrict__ ndi,
                                   const float* __restrict__ nx,
                                   const int* __restrict__ idxv,
                                   float* __restrict__ out_q,
                                   float* __restrict__ out_idxf,
                                   float* __restrict__ partials) {
    int w = threadIdx.x >> 6, lane = threadIdx.x & 63;
    int row = blockIdx.x * 4 + w;
    int iv = idxv[row];
    float ndif = (float)ndi[iv];
    float inx = 1.0f / nx[row];
    float4 q4 = ((const float4*)(cb + (size_t)iv * DIM))[lane];
    float4 x4 = ((const float4*)(x + (size_t)row * DIM))[lane];
    float4 qq;
    qq.x = q4.x * ndif; qq.y = q4.y * ndif;
    qq.z = q4.z * ndif; qq.w = q4.w * ndif;
    ((float4*)(out_q + (size_t)row * DIM))[lane] = qq;
    float dx = qq.x - x4.x * inx;
    float dy = qq.y - x4.y * inx;
    float dz = qq.z - x4.z * inx;
    float dw = qq.w - x4.w * inx;
    float ss = dx * dx + dy * dy + dz * dz + dw * dw;
    #pragma unroll
    for (int off = 32; off > 0; off >>= 1) ss += __shfl_down(ss, off);
    if (lane == 0) {
        partials[row] = ss;
        out_idxf[row] = (float)iv;
    }
}

// ---------------- final deterministic loss reduction
__global__ void loss_reduce_kernel(const float* __restrict__ partials,
                                   float* __restrict__ out_loss) {
    int t = threadIdx.x;
    float s = 0.0f;
    for (int i = t; i < N_ROWS; i += 256) s += partials[i];
    __shared__ float red[4];
    #pragma unroll
    for (int off = 32; off > 0; off >>= 1) s += __shfl_down(s, off);
    if ((t & 63) == 0) red[t >> 6] = s;
    __syncthreads();
    if (t == 0) out_loss[0] = 1.25f * (red[0] + red[1] + red[2] + red[3]) / (float)(N_ROWS * DIM);
}

extern "C" void kernel_launch(void* const* d_in, const int* in_sizes, int n_in,
                              void* d_out, int out_size, void* d_ws, size_t ws_size,
                              hipStream_t stream) {
    const float* x  = (const float*)d_in[0];
    const float* cb = (const float*)d_in[1];
    float* out = (float*)d_out;

    // doubles first (alignment), then f32/i32, then pk.  Total ~= 8.5 MB.
    double* c2d  = (double*)d_ws;                       // 4096 dbl
    double* ndi  = c2d + NCODE;                         // 4096 dbl
    double* pb_s = ndi + NCODE;                         // 65536*4 dbl (2MB)
    float*  c2   = (float*)(pb_s + (size_t)N_ROWS * NCH);  // 4096
    float*  nx   = c2 + NCODE;                          // 65536
    float*  scx  = nx + N_ROWS;                         // 65536
    int*    idxv = (int*)(scx + N_ROWS);                // 65536
    float*  partials = (float*)(idxv + N_ROWS);         // 65536
    int*    counter  = (int*)(partials + N_ROWS);       // 8 ints
    int*    rowlist  = counter + 8;                     // 65536
    int*    pb_i     = rowlist + N_ROWS;                // 65536*4 (1MB)
    unsigned short* pk = (unsigned short*)(pb_i + (size_t)N_ROWS * NCH);  // 4MB

    float* out_q    = out;
    float* out_loss = out + (size_t)N_ROWS * DIM;
    float* out_idxf = out_loss + 1;

    hipLaunchKernelGGL(prep_kernel, dim3(NCODE + N_ROWS / 4), dim3(256), 0, stream,
                       cb, x, pk, c2, c2d, ndi, nx, scx, counter);
    hipLaunchKernelGGL(argmin_mfma_kernel, dim3(N_ROWS / 128), dim3(256), 0, stream,
                       x, pk, c2, scx, idxv, counter, rowlist);
    hipLaunchKernelGGL(fixup2d_kernel, dim3(FIXG), dim3(256), 0, stream,
                       x, cb, c2d, ndi, counter, rowlist, pb_s, pb_i);
    hipLaunchKernelGGL(fixmerge_kernel, dim3(64), dim3(256), 0, stream,
                       counter, rowlist, pb_s, pb_i, idxv);
    hipLaunchKernelGGL(gather_loss_kernel, dim3(N_ROWS / 4), dim3(256), 0, stream,
                       x, cb, ndi, nx, idxv, out_q, out_idxf, partials);
    hipLaunchKernelGGL(loss_reduce_kernel, dim3(1), dim3(256), 0, stream,
                       partials, out_loss);
}

// Round 20
// 554.521 us; speedup vs baseline: 1.8196x; 1.0805x over previous
//
#include <hip/hip_runtime.h>
#include <math.h>

#define N_ROWS 65536
#define DIM    256
#define NCODE  4096
#define MARGIN 2e-4f
#define TILE_C 32
#define NTILE  (NCODE / TILE_C)   // 128
#define FB     8                  // fixup rows per batch
#define KCH    1024               // fixup codes per chunk
#define NCH    (NCODE / KCH)      // 4
#define FIXG   512

typedef __attribute__((ext_vector_type(8)))  short short8v;
typedef __attribute__((ext_vector_type(4)))  float float4v;
typedef __attribute__((ext_vector_type(16))) float f32x16;

__device__ inline unsigned short f2bf(float f) {
    unsigned u = __float_as_uint(f);
    unsigned r = (u + 0x7fffu + ((u >> 16) & 1u)) >> 16;
    return (unsigned short)r;
}
__device__ inline float bf2f(unsigned short h) {
    return __uint_as_float(((unsigned)h) << 16);
}
__device__ inline void gll16(const void* g, void* l) {
    __builtin_amdgcn_global_load_lds(
        (const __attribute__((address_space(1))) unsigned int*)g,
        (__attribute__((address_space(3))) unsigned int*)l, 16, 0, 0);
}

// ---------------- fused prep: blocks [0,NCODE) = codebook normalize+pack,
// blocks [NCODE, NCODE+N_ROWS/16) = x norms (16 rows each: 4/wave) + fslot zero.
__global__ void prep_kernel(const float* __restrict__ cb,
                            const float* __restrict__ x,
                            unsigned short* __restrict__ pk,
                            float* __restrict__ c2,
                            double* __restrict__ c2d,
                            double* __restrict__ ndi,
                            float* __restrict__ nx,
                            float* __restrict__ scx,
                            int* __restrict__ counter,
                            int* __restrict__ fslot) {
    int t = threadIdx.x;
    if (blockIdx.x < NCODE) {
        int k = blockIdx.x;
        float v = cb[k * DIM + t];
        double dv = (double)v;
        double ss = dv * dv;
        __shared__ double red2[4], red3[4], redn[4];
        #pragma unroll
        for (int off = 32; off > 0; off >>= 1) ss += __shfl_down(ss, off);
        if ((t & 63) == 0) redn[t >> 6] = ss;
        __syncthreads();
        double S = redn[0] + redn[1] + redn[2] + redn[3];
        double nrm = fmax(sqrt(S), 1e-12);
        double cq = dv / nrm;
        float cf = (float)cq;
        unsigned short hb = f2bf(cf);
        unsigned short lb = f2bf(cf - bf2f(hb));
        {
            int cb32 = k >> 5, klo = k & 31, ks = t >> 4, hi = (t >> 3) & 1, j = t & 7;
            size_t ch = ((size_t)cb32 * 16 + ks) * 2;
            size_t slot = (size_t)(hi * 32 + klo) * 8 + j;
            pk[(ch + 0) * 512 + slot] = hb;
            pk[(ch + 1) * 512 + slot] = lb;
        }
        double s2 = (double)cf * (double)cf;
        double s3 = cq * cq;
        #pragma unroll
        for (int off = 32; off > 0; off >>= 1) {
            s2 += __shfl_down(s2, off);
            s3 += __shfl_down(s3, off);
        }
        if ((t & 63) == 0) { red2[t >> 6] = s2; red3[t >> 6] = s3; }
        __syncthreads();
        if (t == 0) {
            c2[k]  = (float)(red2[0] + red2[1] + red2[2] + red2[3]);
            c2d[k] = red3[0] + red3[1] + red3[2] + red3[3];
            ndi[k] = 1.0 / nrm;
        }
    } else {
        int xb = blockIdx.x - NCODE;
        if (xb == 0 && t == 0) counter[0] = 0;
        int w = t >> 6;
        int lane = t & 63;
        if (t < 16) fslot[xb * 16 + t] = 0;
        #pragma unroll
        for (int r = 0; r < 4; r++) {
            int row = xb * 16 + w * 4 + r;
            float4 v = ((const float4*)(x + (size_t)row * DIM))[lane];
            double ss = (double)v.x * v.x + (double)v.y * v.y
                      + (double)v.z * v.z + (double)v.w * v.w;
            #pragma unroll
            for (int off = 32; off > 0; off >>= 1) ss += __shfl_down(ss, off);
            if (lane == 0) {
                double n = fmax(sqrt(ss), 1e-12);
                nx[row]  = (float)n;
                scx[row] = (float)(2.0 / n);
            }
        }
    }
}

// ---------------- main: 3-pass split-bf16 32x32x16 MFMA + EXACT top-2 + gap flag.
// R17/R19 proven structure; flagged rows also record their slot in fslot[row].
__attribute__((amdgpu_waves_per_eu(2, 2)))
__global__ void __launch_bounds__(256)
argmin_mfma_kernel(const float* __restrict__ x,
                   const unsigned short* __restrict__ pk,
                   const float* __restrict__ c2,
                   const float* __restrict__ scx,
                   int* __restrict__ idx_out,
                   int* __restrict__ counter,
                   int* __restrict__ rowlist,
                   int* __restrict__ fslot) {
    __shared__ unsigned short buf[2][16384];   // 2 x 32KB
    __shared__ float c2s[NCODE];               // 16KB

    int tid  = threadIdx.x;
    int lane = tid & 63;
    int wave = tid >> 6;
    int cl31 = lane & 31;
    int hi   = lane >> 5;
    int xbase = blockIdx.x * 128 + wave * 32;

    // ---- stage c2 into LDS (once)
    #pragma unroll
    for (int i = 0; i < NCODE / 256; i++) c2s[i * 256 + tid] = c2[i * 256 + tid];

    // ---- load + split X fragments: B-frag row = lane&31, k = hi*8+j
    short8v bh[16], bl[16];
    const float* xr = x + (size_t)(xbase + cl31) * DIM + hi * 8;
    #pragma unroll
    for (int ks = 0; ks < 16; ks++) {
        float4 f0 = *(const float4*)(xr + ks * 16);
        float4 f1 = *(const float4*)(xr + ks * 16 + 4);
        float e[8] = {f0.x, f0.y, f0.z, f0.w, f1.x, f1.y, f1.z, f1.w};
        short8v h, l;
        #pragma unroll
        for (int j = 0; j < 8; j++) {
            unsigned short hb = f2bf(e[j]);
            h[j] = (short)hb;
            l[j] = (short)f2bf(e[j] - bf2f(hb));
        }
        bh[ks] = h;
        bl[ks] = l;
    }
    float scr = scx[xbase + cl31];

    float s1 = 3.4e38f, s2 = 3.4e38f;
    int   i1 = 0x7fffffff;

    // ---- stage tile 0 (each wave: 8 chunks, linear 1KB each)
    {
        const unsigned short* src = pk + ((size_t)wave * 8) * 512 + lane * 8;
        unsigned short* dst = &buf[0][(wave * 8) * 512];
        #pragma unroll
        for (int i = 0; i < 8; i++) gll16(src + i * 512, dst + i * 512);
    }
    __syncthreads();

    int cur = 0;
    for (int t = 0; t < NTILE; t++) {
        int cbb = t * TILE_C;

        if (t + 1 < NTILE) {
            const unsigned short* src =
                pk + ((size_t)(t + 1) * 32 + wave * 8) * 512 + lane * 8;
            unsigned short* dst = &buf[cur ^ 1][(wave * 8) * 512];
            #pragma unroll
            for (int i = 0; i < 8; i++) gll16(src + i * 512, dst + i * 512);
        }

        // ---- 48 MFMA from LDS, 3 independent accumulator chains (len 16 each)
        const unsigned short* cbuf = &buf[cur][0];
        f32x16 a1 = {0.f,0.f,0.f,0.f,0.f,0.f,0.f,0.f,0.f,0.f,0.f,0.f,0.f,0.f,0.f,0.f};
        f32x16 a2 = a1, a3 = a1;
        #pragma unroll
        for (int ks = 0; ks < 16; ks++) {
            short8v ah = *(const short8v*)(cbuf + (size_t)(ks * 2 + 0) * 512 + lane * 8);
            short8v al = *(const short8v*)(cbuf + (size_t)(ks * 2 + 1) * 512 + lane * 8);
            a1 = __builtin_amdgcn_mfma_f32_32x32x16_bf16(ah, bh[ks], a1, 0, 0, 0);
            a2 = __builtin_amdgcn_mfma_f32_32x32x16_bf16(ah, bl[ks], a2, 0, 0, 0);
            a3 = __builtin_amdgcn_mfma_f32_32x32x16_bf16(al, bh[ks], a3, 0, 0, 0);
        }

        // ---- epilogue: scores from LDS c2; exact best2 with wave-skip
        float4v gq0 = *(const float4v*)&c2s[cbb + hi * 4];
        float4v gq1 = *(const float4v*)&c2s[cbb + hi * 4 + 8];
        float4v gq2 = *(const float4v*)&c2s[cbb + hi * 4 + 16];
        float4v gq3 = *(const float4v*)&c2s[cbb + hi * 4 + 24];
        float sv[16];
        float mn = 3.4e38f;
        #pragma unroll
        for (int g = 0; g < 4; g++) {
            float4v gg = (g == 0) ? gq0 : (g == 1) ? gq1 : (g == 2) ? gq2 : gq3;
            #pragma unroll
            for (int q = 0; q < 4; q++) {
                int r = g * 4 + q;
                float s = gg[q] - scr * (a1[r] + a2[r] + a3[r]);
                sv[r] = s;
                mn = fminf(mn, s);
            }
        }
        if (!__all(mn >= s2)) {
            #pragma unroll
            for (int g = 0; g < 4; g++) {
                #pragma unroll
                for (int q = 0; q < 4; q++) {
                    float s = sv[g * 4 + q];
                    int ci = cbb + q + 8 * g + 4 * hi;   // ascending per thread
                    if (s < s1) { s2 = s1; s1 = s; i1 = ci; }
                    else if (s < s2) s2 = s;
                }
            }
        }

        __syncthreads();   // drains gll vmcnt; all waves done with cur
        cur ^= 1;
    }

    // ---- merge the two lane-halves (same row, disjoint codes): exact global top-2
    {
        float o1 = __shfl_xor(s1, 32);
        int   oi = __shfl_xor(i1, 32);
        float o2 = __shfl_xor(s2, 32);
        if (o1 < s1 || (o1 == s1 && oi < i1)) { s2 = fminf(s1, o2); s1 = o1; i1 = oi; }
        else                                   { s2 = fminf(o1, s2); }
    }
    if (lane < 32) {
        int row = xbase + lane;
        idx_out[row] = i1;
        if (s2 - s1 < MARGIN) {
            int slot = atomicAdd(counter, 1);
            rowlist[slot] = row;
            fslot[row] = slot + 1;
        }
    }
}

// ---------------- fixup 2D: (8-row batch) x (1024-code chunk) exact f64 partial argmin
__global__ void fixup2d_kernel(const float* __restrict__ x,
                               const float* __restrict__ cb,
                               const double* __restrict__ c2d,
                               const double* __restrict__ ndi,
                               const int* __restrict__ counter,
                               const int* __restrict__ rowlist,
                               double* __restrict__ pb_s,
                               int* __restrict__ pb_i) {
    __shared__ double xs[FB][DIM];        // 16KB
    __shared__ double isx_sh[FB];
    __shared__ double red_s[4][FB];
    __shared__ int    red_i[4][FB];
    int t = threadIdx.x, lane = t & 63, wave = t >> 6;
    int cnt = counter[0];
    int nbat = (cnt + FB - 1) / FB;
    int nwork = nbat * NCH;

    for (int w = blockIdx.x; w < nwork; w += FIXG) {
        int batch = w / NCH, chunk = w - batch * NCH;
        int base = batch * FB;
        int nb = cnt - base; if (nb > FB) nb = FB;

        #pragma unroll
        for (int r = 0; r < FB; r++)
            if (r < nb) xs[r][t] = (double)x[(size_t)rowlist[base + r] * DIM + t];
        __syncthreads();

        for (int rr = wave; rr < nb; rr += 4) {
            double a0 = xs[rr][lane],       a1 = xs[rr][lane + 64];
            double a2 = xs[rr][lane + 128], a3 = xs[rr][lane + 192];
            double ss = a0 * a0 + a1 * a1 + a2 * a2 + a3 * a3;
            #pragma unroll
            for (int m = 1; m < 64; m <<= 1) ss += __shfl_xor(ss, m);
            if (lane == 0) isx_sh[rr] = 2.0 / fmax(sqrt(ss), 1e-12);
        }
        __syncthreads();

        double bs[FB]; int bi[FB];
        #pragma unroll
        for (int r = 0; r < FB; r++) { bs[r] = 1e300; bi[r] = 0x7fffffff; }

        for (int k0 = 0; k0 < KCH / 256; k0++) {
            int k = chunk * KCH + k0 * 256 + t;
            const float4* cr = (const float4*)(cb + (size_t)k * DIM);
            double d[FB];
            #pragma unroll
            for (int r = 0; r < FB; r++) d[r] = 0.0;
            #pragma unroll 4
            for (int d4 = 0; d4 < DIM / 4; d4++) {
                float4 c = cr[d4];
                double cx = c.x, cy = c.y, cz = c.z, cw = c.w;
                int dd = d4 * 4;
                #pragma unroll
                for (int r = 0; r < FB; r++) {
                    d[r] = fma(cx, xs[r][dd],     d[r]);
                    d[r] = fma(cy, xs[r][dd + 1], d[r]);
                    d[r] = fma(cz, xs[r][dd + 2], d[r]);
                    d[r] = fma(cw, xs[r][dd + 3], d[r]);
                }
            }
            double ndik = ndi[k], c2k = c2d[k];
            #pragma unroll
            for (int r = 0; r < FB; r++) {
                double sc = c2k - isx_sh[r] * d[r] * ndik;
                if (sc < bs[r] || (sc == bs[r] && k < bi[r])) { bs[r] = sc; bi[r] = k; }
            }
        }

        #pragma unroll
        for (int r = 0; r < FB; r++) {
            double b = bs[r]; int idx = bi[r];
            #pragma unroll
            for (int m = 1; m < 64; m <<= 1) {
                double ob = __shfl_xor(b, m);
                int   oi = __shfl_xor(idx, m);
                if (ob < b || (ob == b && oi < idx)) { b = ob; idx = oi; }
            }
            if (lane == 0) { red_s[wave][r] = b; red_i[wave][r] = idx; }
        }
        __syncthreads();
        if (t < nb) {
            double b = red_s[0][t]; int idx = red_i[0][t];
            #pragma unroll
            for (int ww = 1; ww < 4; ww++) {
                double ob = red_s[ww][t]; int oi = red_i[ww][t];
                if (ob < b || (ob == b && oi < idx)) { b = ob; idx = oi; }
            }
            pb_s[(size_t)(base + t) * NCH + chunk] = b;
            pb_i[(size_t)(base + t) * NCH + chunk] = idx;
        }
        __syncthreads();
    }
}

// ---------------- gather + inline fix-merge + per-row loss partial (4 rows/block)
__global__ void gather_loss_kernel(const float* __restrict__ x,
                                   const float* __restrict__ cb,
                                   const double* __restrict__ ndi,
                                   const float* __restrict__ nx,
                                   const int* __restrict__ idxv,
                                   const int* __restrict__ fslot,
                                   const double* __restrict__ pb_s,
                                   const int* __restrict__ pb_i,
                                   float* __restrict__ out_q,
                                   float* __restrict__ out_idxf,
                                   float* __restrict__ partials) {
    int w = threadIdx.x >> 6, lane = threadIdx.x & 63;
    int row = blockIdx.x * 4 + w;
    int fs = fslot[row];
    int iv;
    if (fs > 0) {
        int s = fs - 1;
        double b = pb_s[(size_t)s * NCH]; iv = pb_i[(size_t)s * NCH];
        #pragma unroll
        for (int c = 1; c < NCH; c++) {
            double ob = pb_s[(size_t)s * NCH + c]; int oi = pb_i[(size_t)s * NCH + c];
            if (ob < b || (ob == b && oi < iv)) { b = ob; iv = oi; }
        }
    } else {
        iv = idxv[row];
    }
    float ndif = (float)ndi[iv];
    float inx = 1.0f / nx[row];
    float4 q4 = ((const float4*)(cb + (size_t)iv * DIM))[lane];
    float4 x4 = ((const float4*)(x + (size_t)row * DIM))[lane];
    float4 qq;
    qq.x = q4.x * ndif; qq.y = q4.y * ndif;
    qq.z = q4.z * ndif; qq.w = q4.w * ndif;
    ((float4*)(out_q + (size_t)row * DIM))[lane] = qq;
    float dx = qq.x - x4.x * inx;
    float dy = qq.y - x4.y * inx;
    float dz = qq.z - x4.z * inx;
    float dw = qq.w - x4.w * inx;
    float ss = dx * dx + dy * dy + dz * dz + dw * dw;
    #pragma unroll
    for (int off = 32; off > 0; off >>= 1) ss += __shfl_down(ss, off);
    if (lane == 0) {
        partials[row] = ss;
        out_idxf[row] = (float)iv;
    }
}

// ---------------- final deterministic loss reduction (float4 loads)
__global__ void loss_reduce_kernel(const float* __restrict__ partials,
                                   float* __restrict__ out_loss) {
    int t = threadIdx.x;
    float s = 0.0f;
    const float4* p4 = (const float4*)partials;
    for (int i = t; i < N_ROWS / 4; i += 256) {
        float4 v = p4[i];
        s += v.x + v.y + v.z + v.w;
    }
    __shared__ float red[4];
    #pragma unroll
    for (int off = 32; off > 0; off >>= 1) s += __shfl_down(s, off);
    if ((t & 63) == 0) red[t >> 6] = s;
    __syncthreads();
    if (t == 0) out_loss[0] = 1.25f * (red[0] + red[1] + red[2] + red[3]) / (float)(N_ROWS * DIM);
}

extern "C" void kernel_launch(void* const* d_in, const int* in_sizes, int n_in,
                              void* d_out, int out_size, void* d_ws, size_t ws_size,
                              hipStream_t stream) {
    const float* x  = (const float*)d_in[0];
    const float* cb = (const float*)d_in[1];
    float* out = (float*)d_out;

    // doubles first (alignment), then f32/i32, then pk.  Total ~= 8.8 MB.
    double* c2d  = (double*)d_ws;                       // 4096 dbl
    double* ndi  = c2d + NCODE;                         // 4096 dbl
    double* pb_s = ndi + NCODE;                         // 65536*4 dbl (2MB)
    float*  c2   = (float*)(pb_s + (size_t)N_ROWS * NCH);  // 4096
    float*  nx   = c2 + NCODE;                          // 65536
    float*  scx  = nx + N_ROWS;                         // 65536
    int*    idxv = (int*)(scx + N_ROWS);                // 65536
    float*  partials = (float*)(idxv + N_ROWS);         // 65536
    int*    counter  = (int*)(partials + N_ROWS);       // 8 ints
    int*    rowlist  = counter + 8;                     // 65536
    int*    fslot    = rowlist + N_ROWS;                // 65536
    int*    pb_i     = fslot + N_ROWS;                  // 65536*4 (1MB)
    unsigned short* pk = (unsigned short*)(pb_i + (size_t)N_ROWS * NCH);  // 4MB

    float* out_q    = out;
    float* out_loss = out + (size_t)N_ROWS * DIM;
    float* out_idxf = out_loss + 1;

    hipLaunchKernelGGL(prep_kernel, dim3(NCODE + N_ROWS / 16), dim3(256), 0, stream,
                       cb, x, pk, c2, c2d, ndi, nx, scx, counter, fslot);
    hipLaunchKernelGGL(argmin_mfma_kernel, dim3(N_ROWS / 128), dim3(256), 0, stream,
                       x, pk, c2, scx, idxv, counter, rowlist, fslot);
    hipLaunchKernelGGL(fixup2d_kernel, dim3(FIXG), dim3(256), 0, stream,
                       x, cb, c2d, ndi, counter, rowlist, pb_s, pb_i);
    hipLaunchKernelGGL(gather_loss_kernel, dim3(N_ROWS / 4), dim3(256), 0, stream,
                       x, cb, ndi, nx, idxv, fslot, pb_s, pb_i, out_q, out_idxf, partials);
    hipLaunchKernelGGL(loss_reduce_kernel, dim3(1), dim3(256), 0, stream,
                       partials, out_loss);
}